// Round 4
// baseline (197.514 us; speedup 1.0000x reference)
//
#include <hip/hip_runtime.h>

// Problem constants (fixed by the reference)
#define N_MOL 2048
#define P_PRO 2048
#define HID   64
#define HEADS 16
#define NGRAPH 64

// Workspace layout (float offsets):
//   pe_mol [2048*16][2] @ 0       interleaved {a_mol, exp(a_mol)}
//   pe_pro [2048*16][2] @ 65536   interleaved {a_pro, exp(a_pro)}
//   y_part [4][2048*16] @ 131072  per-p-tile partial row sums
//   cnt    (int)        @ 262144  k2 block-done counter (zeroed by k1)
#define OFF_PEPRO 65536
#define OFF_YPART 131072
#define OFF_CNT   262144

// ---------------------------------------------------------------------------
// Kernel 1: a_mol = mol @ Wmu[:64] + bmu ; a_pro = pro @ Wmu[64:]
// Stores interleaved {a, exp(a)} float2 so k2 needs one vector load per pair.
// 256 blocks x 256 threads; each block = 16 rows x 16 heads.
// Block 0 also zeroes the k2 done-counter (ws is re-poisoned every launch).
// ---------------------------------------------------------------------------
__global__ __launch_bounds__(256) void k1_proj(
    const float* __restrict__ mol, const float* __restrict__ pro,
    const float* __restrict__ Wmu, const float* __restrict__ bmu,
    float* __restrict__ ws)
{
    __shared__ float fs[16 * 64];   // 16 rows of features
    __shared__ float wsh[64 * 16];  // 64x16 weight half
    const int tid = threadIdx.x;
    const int blk = blockIdx.x;
    if (blk == 0 && tid == 0) ((int*)(ws + OFF_CNT))[0] = 0;

    const bool isMol = blk < (N_MOL / 16);
    const int rowbase = (isMol ? blk : blk - (N_MOL / 16)) * 16;
    const float* feats = isMol ? (mol + rowbase * HID) : (pro + rowbase * HID);
    const float* wsrc  = Wmu + (isMol ? 0 : HID * HEADS);

    ((float4*)fs)[tid]  = ((const float4*)feats)[tid];
    ((float4*)wsh)[tid] = ((const float4*)wsrc)[tid];
    __syncthreads();

    const int h = tid & 15, r = tid >> 4;
    float acc = isMol ? bmu[h] : 0.0f;
#pragma unroll
    for (int k = 0; k < 64; ++k)
        acc += fs[r * 64 + k] * wsh[k * 16 + h];

    float2* pe = (float2*)(ws + (isMol ? 0 : OFF_PEPRO));
    const int idx = (rowbase + r) * 16 + h;
    float2 v; v.x = acc; v.y = __expf(acc);
    pe[idx] = v;
}

// ---------------------------------------------------------------------------
// Kernel 2: y_part[pt][n][h] = sum over p-tile of (elu(a_mol+a_pro)+1)
// Identity: elu(x)+1 = med3(x+1, exp(x), 1)   [x>0: 1<x+1<e^x -> x+1;
//                                              x<=0: x+1<e^x<=1 -> e^x]
// -> 4 VALU ops/pair (add, mul, v_med3_f32, add), exp hoisted to k1.
// Grid: 1024 blocks = 256 n-tiles (8 rows) x 4 p-tiles (512 p's each).
// Each thread: float4 load = 2 pair-columns (heads h0,h0+1) x 8 rows.
// Last-block-done fuses the segment-sum + MLP head (saves the k3 launch).
// ---------------------------------------------------------------------------
__global__ __launch_bounds__(256) void k2_pair(
    const float* __restrict__ ws_in, const int* __restrict__ batch,
    const float* __restrict__ W1, const float* __restrict__ b1,
    const float* __restrict__ W2, const float* __restrict__ b2,
    float* __restrict__ y_part, int* __restrict__ cnt,
    float* __restrict__ out)
{
    const float4* pe_mol4 = (const float4*)ws_in;
    const float4* pe_pro4 = (const float4*)(ws_in + OFF_PEPRO);

    const int tid = threadIdx.x;
    const int hf = tid & 7;        // head-pair: heads {2hf, 2hf+1}
    const int nt = blockIdx.x >> 2, pt = blockIdx.x & 3;
    const int nbase = nt * 8;
    const int pbase4 = pt * 4096;  // float4 units: 512*16*2 floats / 4

    float a10[8], a11[8], ea0[8], ea1[8], acc0[8], acc1[8];
#pragma unroll
    for (int j = 0; j < 8; ++j) {
        const float4 m = pe_mol4[(nbase + j) * 8 + hf];
        a10[j] = m.x + 1.0f; ea0[j] = m.y;
        a11[j] = m.z + 1.0f; ea1[j] = m.w;
        acc0[j] = 0.0f; acc1[j] = 0.0f;
    }

#pragma unroll 4
    for (int i = 0; i < 16; ++i) {
        const float4 p = pe_pro4[pbase4 + i * 256 + tid];
#pragma unroll
        for (int j = 0; j < 8; ++j) {
            acc0[j] += __builtin_amdgcn_fmed3f(a10[j] + p.x, ea0[j] * p.y, 1.0f);
            acc1[j] += __builtin_amdgcn_fmed3f(a11[j] + p.z, ea1[j] * p.w, 1.0f);
        }
    }

    // Block reduction over the 32 p-groups per (row j, head h)
    __shared__ float red[8 * 32 * 16];   // 16 KB
#pragma unroll
    for (int j = 0; j < 8; ++j)
        ((float2*)red)[j * 256 + tid] = make_float2(acc0[j], acc1[j]);
    __syncthreads();
    if (tid < 128) {
        const int j = tid >> 4, hh = tid & 15;
        float s = 0.0f;
#pragma unroll
        for (int g2 = 0; g2 < 32; ++g2)
            s += red[j * 512 + g2 * 16 + hh];
        y_part[pt * 32768 + (nbase + j) * 16 + hh] = s;
    }

    // --- last-block-done: fused segment-sum + MLP tail ---
    __threadfence();                    // release y_part to device scope
    __syncthreads();
    __shared__ int s_last;
    if (tid == 0) s_last = (atomicAdd(cnt, 1) == (int)gridDim.x - 1) ? 1 : 0;
    __syncthreads();
    if (!s_last) return;
    __threadfence();                    // acquire: see all blocks' y_part

    // Stage sorted batch ids, binary-search the 65 segment bounds
    __shared__ int sb[N_MOL];           // 8 KB
    for (int i = tid; i < N_MOL; i += 256) sb[i] = batch[i];
    __syncthreads();
    __shared__ int bnd[NGRAPH + 1];
    if (tid <= NGRAPH) {
        const int b = tid;              // lower_bound: first i with sb[i] >= b
        int lo = 0, hi = N_MOL;
        while (lo < hi) { const int mid = (lo + hi) >> 1;
                          if (sb[mid] < b) lo = mid + 1; else hi = mid; }
        bnd[b] = lo;
    }
    __syncthreads();

    // ysum[b][h]: 1024 tasks over 256 threads, coalesced 16-lane segments
    __shared__ float ysum[NGRAPH * HEADS];
#pragma unroll
    for (int k = 0; k < 4; ++k) {
        const int task = tid + k * 256;
        const int b = task >> 4, hh = task & 15;
        const int s0 = bnd[b], e0 = bnd[b + 1];
        float s = 0.0f;
        for (int n = s0; n < e0; ++n) {
            const int o = n * 16 + hh;
            s += (y_part[o] + y_part[32768 + o]) +
                 (y_part[65536 + o] + y_part[98304 + o]);
        }
        ysum[b * 16 + hh] = s * 0.001f;
    }
    __syncthreads();

    // MLP: 8 half-wave groups x 8 graphs; 32 hidden units per group
    const int j = tid & 31, grp = tid >> 5;
#pragma unroll
    for (int bb = 0; bb < 8; ++bb) {
        const int b = grp * 8 + bb;
        float t = b1[j];
#pragma unroll
        for (int hh = 0; hh < HEADS; ++hh) t += ysum[b * 16 + hh] * W1[hh * 32 + j];
        t = (t > 0.0f) ? t : (__expf(t) - 1.0f);   // elu
        float v = t * W2[j];
#pragma unroll
        for (int off = 16; off > 0; off >>= 1) v += __shfl_down(v, off, 32);
        if (j == 0) out[b] = v + b2[0];
    }
}

extern "C" void kernel_launch(void* const* d_in, const int* in_sizes, int n_in,
                              void* d_out, int out_size, void* d_ws, size_t ws_size,
                              hipStream_t stream) {
    const float* mol   = (const float*)d_in[0];
    const float* pro   = (const float*)d_in[1];
    const float* Wmu   = (const float*)d_in[2];
    const float* bmu   = (const float*)d_in[3];
    const float* W1    = (const float*)d_in[4];
    const float* b1    = (const float*)d_in[5];
    const float* W2    = (const float*)d_in[6];
    const float* b2    = (const float*)d_in[7];
    const int*   batch = (const int*)d_in[8];
    float* ws = (float*)d_ws;

    hipLaunchKernelGGL(k1_proj, dim3(256), dim3(256), 0, stream,
                       mol, pro, Wmu, bmu, ws);
    hipLaunchKernelGGL(k2_pair, dim3(1024), dim3(256), 0, stream,
                       ws, batch, W1, b1, W2, b2,
                       ws + OFF_YPART, (int*)(ws + OFF_CNT), (float*)d_out);
}

// Round 5
// 86.440 us; speedup vs baseline: 2.2850x; 2.2850x over previous
//
#include <hip/hip_runtime.h>

// Problem constants (fixed by the reference)
#define N_MOL 2048
#define P_PRO 2048
#define HID   64
#define HEADS 16
#define NGRAPH 64

// Workspace layout (float offsets):
//   pe_mol [2048*16][2] @ 0       interleaved {a_mol, exp(a_mol)}
//   pe_pro [2048*16][2] @ 65536   interleaved {a_pro, exp(a_pro)}
//   y_part [4][2048*16] @ 131072  per-p-tile partial row sums
#define OFF_PEPRO 65536
#define OFF_YPART 131072

// NOTE (R4 lesson): do NOT fuse the tail via last-block-done + __threadfence.
// Agent-scope fences on gfx950 emit L2 writeback/invalidate (per-XCD L2s are
// non-coherent); 1024 blocks doing that serialized into a 140 us stall
// (VALUBusy 4.7%). A kernel boundary is the cheap device-wide sync.

// ---------------------------------------------------------------------------
// Kernel 1: a_mol = mol @ Wmu[:64] + bmu ; a_pro = pro @ Wmu[64:]
// Stores interleaved {a, exp(a)} float2 so k2 needs one vector load per pair.
// 256 blocks x 256 threads; each block = 16 rows x 16 heads.
// ---------------------------------------------------------------------------
__global__ __launch_bounds__(256) void k1_proj(
    const float* __restrict__ mol, const float* __restrict__ pro,
    const float* __restrict__ Wmu, const float* __restrict__ bmu,
    float* __restrict__ ws)
{
    __shared__ float fs[16 * 64];   // 16 rows of features
    __shared__ float wsh[64 * 16];  // 64x16 weight half
    const int tid = threadIdx.x;
    const int blk = blockIdx.x;
    const bool isMol = blk < (N_MOL / 16);
    const int rowbase = (isMol ? blk : blk - (N_MOL / 16)) * 16;
    const float* feats = isMol ? (mol + rowbase * HID) : (pro + rowbase * HID);
    const float* wsrc  = Wmu + (isMol ? 0 : HID * HEADS);

    ((float4*)fs)[tid]  = ((const float4*)feats)[tid];
    ((float4*)wsh)[tid] = ((const float4*)wsrc)[tid];
    __syncthreads();

    const int h = tid & 15, r = tid >> 4;
    float acc = isMol ? bmu[h] : 0.0f;
#pragma unroll
    for (int k = 0; k < 64; ++k)
        acc += fs[r * 64 + k] * wsh[k * 16 + h];

    float2* pe = (float2*)(ws + (isMol ? 0 : OFF_PEPRO));
    const int idx = (rowbase + r) * 16 + h;
    float2 v; v.x = acc; v.y = __expf(acc);
    pe[idx] = v;            // 8B/lane, consecutive h -> fully coalesced
}

// ---------------------------------------------------------------------------
// Kernel 2: y_part[pt][n][h] = sum over p-tile of (elu(a_mol+a_pro)+1)
// Identity: elu(x)+1 = med3(x+1, exp(x), 1)   [x>0: 1<x+1<e^x -> x+1;
//                                              x<=0: x+1<=e^x<=1 -> e^x]
// -> 4 VALU ops/pair (add, mul, v_med3_f32, add), exp hoisted to k1.
// Grid: 1024 blocks = 256 n-tiles (8 rows) x 4 p-tiles (512 p's each).
// Each thread: one float4 load/iter = 2 pair-columns (heads 2hf,2hf+1),
// flat index pbase4 + i*256 + tid -> fully coalesced. NO atomics, NO fences.
// ---------------------------------------------------------------------------
__global__ __launch_bounds__(256) void k2_pair(
    const float* __restrict__ ws_in, float* __restrict__ y_part)
{
    const float4* pe_mol4 = (const float4*)ws_in;
    const float4* pe_pro4 = (const float4*)(ws_in + OFF_PEPRO);

    const int tid = threadIdx.x;
    const int hf = tid & 7;        // head-pair: heads {2hf, 2hf+1}
    const int nt = blockIdx.x >> 2, pt = blockIdx.x & 3;
    const int nbase = nt * 8;
    const int pbase4 = pt * 4096;  // float4 units: 512*16*2 floats / 4

    float a10[8], a11[8], ea0[8], ea1[8], acc0[8], acc1[8];
#pragma unroll
    for (int j = 0; j < 8; ++j) {
        const float4 m = pe_mol4[(nbase + j) * 8 + hf];
        a10[j] = m.x + 1.0f; ea0[j] = m.y;
        a11[j] = m.z + 1.0f; ea1[j] = m.w;
        acc0[j] = 0.0f; acc1[j] = 0.0f;
    }

#pragma unroll 4
    for (int i = 0; i < 16; ++i) {
        const float4 p = pe_pro4[pbase4 + i * 256 + tid];
#pragma unroll
        for (int j = 0; j < 8; ++j) {
            acc0[j] += __builtin_amdgcn_fmed3f(a10[j] + p.x, ea0[j] * p.y, 1.0f);
            acc1[j] += __builtin_amdgcn_fmed3f(a11[j] + p.z, ea1[j] * p.w, 1.0f);
        }
    }

    // Block reduction over the 32 p-groups per (row j, head h)
    __shared__ float red[8 * 32 * 16];   // 16 KB -> 10 blocks/CU
#pragma unroll
    for (int j = 0; j < 8; ++j)
        ((float2*)red)[j * 256 + tid] = make_float2(acc0[j], acc1[j]);
    __syncthreads();
    if (tid < 128) {
        const int j = tid >> 4, hh = tid & 15;
        float s = 0.0f;
#pragma unroll
        for (int g2 = 0; g2 < 32; ++g2)
            s += red[j * 512 + g2 * 16 + hh];
        y_part[pt * 32768 + (nbase + j) * 16 + hh] = s;
    }
}

// ---------------------------------------------------------------------------
// Kernel 3: per-graph segment-sum + fused MLP head.
// 64 blocks (one per graph) x 256 threads. batch is SORTED, so graph b owns
// a contiguous row range [start,end) — found in parallel, summed coalesced.
// ---------------------------------------------------------------------------
__global__ __launch_bounds__(256) void k3_seg_mlp(
    const float* __restrict__ y_part, const int* __restrict__ batch,
    const float* __restrict__ W1, const float* __restrict__ b1,
    const float* __restrict__ W2, const float* __restrict__ b2,
    float* __restrict__ out)
{
    const int tid = threadIdx.x;
    const int b = blockIdx.x;
    __shared__ int s_start, s_end;
    if (tid == 0) { s_start = 0; s_end = 0; }
    __syncthreads();

    // Range-find in the sorted batch array (empty graph -> [0,0))
    for (int i = tid; i < N_MOL; i += 256) {
        const int bi = batch[i];
        if (bi == b) {
            if (i == 0 || batch[i - 1] != b) s_start = i;
            if (i == N_MOL - 1 || batch[i + 1] != b) s_end = i + 1;
        }
    }
    __syncthreads();

    // Coalesced sum of the 4 p-tile partials over the row range
    const int h = tid & 15, rr = tid >> 4;   // 16 row-lanes x 16 heads
    float s = 0.0f;
    for (int n = s_start + rr; n < s_end; n += 16) {
        const int o = n * 16 + h;
        s += (y_part[o] + y_part[32768 + o]) +
             (y_part[65536 + o] + y_part[98304 + o]);
    }

    __shared__ float red[256];
    __shared__ float ysum[HEADS];
    red[tid] = s;
    __syncthreads();
    if (tid < 16) {
        float c = 0.0f;
#pragma unroll
        for (int r2 = 0; r2 < 16; ++r2) c += red[r2 * 16 + tid];
        ysum[tid] = c * 0.001f;
    }
    __syncthreads();

    // MLP: 32 hidden units on lanes 0..31, shuffle-reduce the output dot
    if (tid < 32) {
        const int j = tid;
        float t = b1[j];
#pragma unroll
        for (int hh = 0; hh < HEADS; ++hh) t += ysum[hh] * W1[hh * 32 + j];
        t = (t > 0.0f) ? t : (__expf(t) - 1.0f);   // elu
        float v = t * W2[j];
#pragma unroll
        for (int off = 16; off > 0; off >>= 1) v += __shfl_down(v, off, 32);
        if (tid == 0) out[b] = v + b2[0];
    }
}

extern "C" void kernel_launch(void* const* d_in, const int* in_sizes, int n_in,
                              void* d_out, int out_size, void* d_ws, size_t ws_size,
                              hipStream_t stream) {
    const float* mol   = (const float*)d_in[0];
    const float* pro   = (const float*)d_in[1];
    const float* Wmu   = (const float*)d_in[2];
    const float* bmu   = (const float*)d_in[3];
    const float* W1    = (const float*)d_in[4];
    const float* b1    = (const float*)d_in[5];
    const float* W2    = (const float*)d_in[6];
    const float* b2    = (const float*)d_in[7];
    const int*   batch = (const int*)d_in[8];
    float* ws = (float*)d_ws;

    hipLaunchKernelGGL(k1_proj, dim3(256), dim3(256), 0, stream,
                       mol, pro, Wmu, bmu, ws);
    hipLaunchKernelGGL(k2_pair, dim3(1024), dim3(256), 0, stream,
                       ws, ws + OFF_YPART);
    hipLaunchKernelGGL(k3_seg_mlp, dim3(NGRAPH), dim3(256), 0, stream,
                       ws + OFF_YPART, batch, W1, b1, W2, b2, (float*)d_out);
}